// Round 3
// baseline (330.955 us; speedup 1.0000x reference)
//
#include <hip/hip_runtime.h>

// Seq2SeqLSTM: H=64, F=8, T=512, P=64, B=1024, fp32 in/out.
// R15 = R12 structure (R14's pdot REVERTED: dot2 is slow-pipe and sits in the
// wave's in-order issue stream -> +24us) with three CP cuts:
//  (1) px: the 4 pchain MFMAs folded into ONE via Tg-in-K packing:
//      k=Tg*8+f, A[m=4q'+Tg][k]=(Tg==q)?x[q'][f]:0 (4 lane-const cndmasks),
//      B[k][n]=Wih[Tg*64+u][f]*sc (lane-static), C=bias quad. C/D layout
//      (row=4q+reg) returns all 4 P-values as one f32x4. MFMA/step 12->9.
//  (2) qgates2: each gate's 2-deep K-chain split into independent halves
//      (C-init P / C-init 0) + one spine-head add -> no dep-chain bubbles.
//  (3) ROWS 72->68: h-write batch stride 544B == 32q mod 128 -> writer lanes
//      tile all 32 banks (was: q0/q2,q1/q3 collide = the 4.9M conflicts).
//      Reads keep balanced 2-per-bank starts {0,2,..,30}; row-span overlap
//      only aliases never-read A-rows (!=4b).
// Topology: MB=4 over 256 blocks; lane (q,col) owns cell (batch q, unit
// wv*16+col); batch b at A-row 4b so C/D row=4q+0 puts gates in acc[.][0];
// fp16 weights/h/x pre-scaled by log2e (2*log2e for g-gate); fused-rcp cell.

#define Hh 64
#define Ff 8
#define Tt 512
#define Pp 64
#define BATCH 1024
#define MB 4
#define NBLK (BATCH / MB)   // 256 blocks
#define ROWS 68             // halves per A row (64 + 4 pad) -- write-conflict-free
#define ABUF (16 * ROWS + 64)
#define XSTRIDE 32          // halves per x step-row: 4 batches * 8

typedef __attribute__((ext_vector_type(8))) _Float16 half8;
typedef __attribute__((ext_vector_type(4))) _Float16 half4;
typedef __attribute__((ext_vector_type(4))) float f32x4;

#define LOG2E  1.44269504088896340736f
#define K2LOG2 2.88538008177792681472f   // 2*log2e

#define MFMA16(a, b, c) __builtin_amdgcn_mfma_f32_16x16x32_f16(a, b, c, 0, 0, 0)

__device__ __forceinline__ float rcp_(float x)  { return __builtin_amdgcn_rcpf(x); }
__device__ __forceinline__ float exp2_(float x) { return __builtin_amdgcn_exp2f(x); }
// A-row swizzle (halves): rows 4b (writers) keep offset 0.
__device__ __forceinline__ int arow_base(int m) { return m * ROWS + (m & 3) * 16; }

// B-fragments: 4 gate tiles, fp16, log2e-pre-scaled (2*log2e for g-gate).
// B layout (16x16x32): lane holds B[k = kc*32 + q*8 + j][n = col].
__device__ __forceinline__ void load_wfrags(
    const float* __restrict__ Whh, int wv, int q, int col,
    half8 w0[4], half8 w1[4])
{
    #pragma unroll
    for (int Tg = 0; Tg < 4; ++Tg) {
        int g = Tg * 64 + wv * 16 + col;
        float sc = (Tg == 2) ? K2LOG2 : LOG2E;
        const float* r0 = Whh + g * 64 + q * 8;
        #pragma unroll
        for (int j = 0; j < 8; ++j) {
            w0[Tg][j] = (_Float16)(r0[j] * sc);
            w1[Tg][j] = (_Float16)(r0[32 + j] * sc);
        }
    }
}

// Gate MFMAs: two INDEPENDENT halves per gate (no C-chain), g-gate first.
// QA C-init carries P (x+bias); QB C-init is zero. gate = QA[0]+QB[0].
__device__ __forceinline__ void qgates2(half8 a0, half8 a1,
    const half8 w0[4], const half8 w1[4], const f32x4 Ci[4], f32x4 Z,
    f32x4 QA[4], f32x4 QB[4])
{
    QA[2] = MFMA16(a0, w0[2], Ci[2]);
    QB[2] = MFMA16(a1, w1[2], Z);
    QA[0] = MFMA16(a0, w0[0], Ci[0]);
    QB[0] = MFMA16(a1, w1[0], Z);
    QA[1] = MFMA16(a0, w0[1], Ci[1]);
    QB[1] = MFMA16(a1, w1[1], Z);
    QA[3] = MFMA16(a0, w0[3], Ci[3]);
    QB[3] = MFMA16(a1, w1[3], Z);
}

// Fused-rcp cell. Spine: add -> eg -> it -> cS fma -> med3 -> ec -> rc -> fma.
__device__ __forceinline__ float cellf2(const f32x4 QA[4], const f32x4 QB[4],
                                        float& cS)
{
    float gg = QA[2][0] + QB[2][0];
    float eg = exp2_(gg);                 // e^{2g} (g-row pre-scaled 2*log2e)
    float gi = QA[0][0] + QB[0][0];
    float ei = exp2_(-gi);
    float it = (eg - 1.f) * rcp_((1.f + ei) * (1.f + eg));   // si*tanh(g)
    float gf = QA[1][0] + QB[1][0];
    float ef = exp2_(-gf);
    float sf = rcp_(1.f + ef);
    float go = QA[3][0] + QB[3][0];
    float eo = exp2_(-go);
    float so   = rcp_(1.f + eo);          // sigmoid(o), off-spine
    float m2so = -2.f * so;
    cS = __builtin_fmaf(sf, cS, K2LOG2 * it);                // cS = 2*log2e*c
    float cc = __builtin_amdgcn_fmed3f(cS, -60.f, 60.f);     // exp2 guard
    float ec = exp2_(cc);                                    // e^{2c}
    float rc = rcp_(1.f + ec);
    return __builtin_fmaf(m2so, rc, so);  // so*tanh(c) = so*(1 - 2/(1+e^{2c}))
}

__global__ __launch_bounds__(256, 1)
void seq2seq_v15(const float* __restrict__ x_seq,
                 const float* __restrict__ eWih, const float* __restrict__ eWhh,
                 const float* __restrict__ ebih, const float* __restrict__ ebhh,
                 const float* __restrict__ dWih, const float* __restrict__ dWhh,
                 const float* __restrict__ dbih, const float* __restrict__ dbhh,
                 const float* __restrict__ fcW,  const float* __restrict__ fcb,
                 float* __restrict__ out)
{
    __shared__ __align__(16) _Float16 xs[(Tt + 2) * XSTRIDE];  // 32.9 KB; predbuf alias
    __shared__ __align__(16) _Float16 A0[ABUF];
    __shared__ __align__(16) _Float16 A1[ABUF];

    const int tid  = threadIdx.x;
    const int wv   = tid >> 6;
    const int lane = tid & 63;
    const int q    = lane >> 4;
    const int col  = lane & 15;
    const int u    = wv * 16 + col;
    const int b0   = blockIdx.x * MB;
    const bool selq = (q == (col & 3));   // px A-mask: lane supplies x iff its
                                          // k-block Tg (=q) matches row col's Tg
    const half8 hz = {};
    const f32x4 Zv = {0.f, 0.f, 0.f, 0.f};

    half8 w0[4], w1[4];
    load_wfrags(eWhh, wv, q, col, w0, w1);

    // px B-fragment: Bx[j] = Wih[gate(Tg=q, u)][j] * sc(q)   (lane-static)
    // px C-init: biasC[r] = (bih+bhh)[r*64+u] * sc(r)
    half8 Bx;
    f32x4 biasC;
    #pragma unroll
    for (int j = 0; j < 8; ++j)
        Bx[j] = (_Float16)(eWih[(q * 64 + u) * 8 + j] * ((q == 2) ? K2LOG2 : LOG2E));
    #pragma unroll
    for (int r = 0; r < 4; ++r)
        biasC[r] = (ebih[r * 64 + u] + ebhh[r * 64 + u]) * ((r == 2) ? K2LOG2 : LOG2E);

    // init: zero A buffers + xs pad rows, stage x (fp32 -> fp16)
    { int* Z0 = (int*)A0; int* Z1 = (int*)A1;
      for (int i = tid; i < ABUF / 2; i += 256) { Z0[i] = 0; Z1[i] = 0; } }
    if (tid < 32) ((int*)xs)[Tt * 16 + tid] = 0;         // zero 2 pad rows
    for (int i = tid; i < MB * Tt * 2; i += 256) {       // 4096 float4s
        int b   = i >> 10;
        int rem = i & 1023;
        int t   = rem >> 1;
        int f4  = (rem & 1) * 4;
        const float* src = x_seq + ((size_t)(b0 + b) * Tt + t) * Ff + f4;
        half4 s = { (_Float16)src[0], (_Float16)src[1], (_Float16)src[2], (_Float16)src[3] };
        *(half4*)(&xs[t * XSTRIDE + b * 8 + f4]) = s;
    }
    __syncthreads();                                     // staging visible

    // per-lane hoisted pointers (swizzled A reads; writers at rows 4b, swizzle 0)
    const _Float16* arA = A0 + arow_base(col) + q * 8;
    const _Float16* arB = A1 + arow_base(col) + q * 8;
    _Float16* hwA = A0 + 4 * q * ROWS + u;
    _Float16* hwB = A1 + 4 * q * ROWS + u;
    const _Float16* xq = xs + (col >> 2) * 8;            // x walker (broadcast groups)

    float cS = 0.f;
    f32x4 Ci[4];
    {   half8 xv = *(const half8*)(xq);                  // x(0)
        half8 ax = selq ? xv : hz;
        f32x4 P4 = MFMA16(ax, Bx, biasC);                // all 4 P-values, 1 MFMA
        Ci[0] = P4;
        Ci[1] = (f32x4){P4[1], P4[1], P4[1], P4[1]};
        Ci[2] = (f32x4){P4[2], P4[2], P4[2], P4[2]};
        Ci[3] = (f32x4){P4[3], P4[3], P4[3], P4[3]};
        xq += XSTRIDE; }

    // ============ encoder: 512 steps, barrier at top, P one step ahead ============
    for (int t = 0; t < Tt; t += 2) {
        __syncthreads();                                 // h(t) visible (A0)
        {
            half8 a0 = *(const half8*)(arA);
            half8 a1 = *(const half8*)(arA + 32);
            half8 xv = *(const half8*)(xq); xq += XSTRIDE;   // x(t+1), off-CP
            f32x4 QA[4], QB[4];
            qgates2(a0, a1, w0, w1, Ci, Zv, QA, QB);
            half8 ax = selq ? xv : hz;                   // fills Qg-latency gap
            f32x4 P4 = MFMA16(ax, Bx, biasC);            // px for t+1 (9th MFMA)
            float hn = cellf2(QA, QB, cS);
            Ci[0] = P4;                                  // splats off-CP
            Ci[1] = (f32x4){P4[1], P4[1], P4[1], P4[1]};
            Ci[2] = (f32x4){P4[2], P4[2], P4[2], P4[2]};
            Ci[3] = (f32x4){P4[3], P4[3], P4[3], P4[3]};
            *hwB = (_Float16)hn;                         // h(t+1) -> A1
        }
        __syncthreads();                                 // h(t+1) visible (A1)
        {
            half8 a0 = *(const half8*)(arB);
            half8 a1 = *(const half8*)(arB + 32);
            half8 xv = *(const half8*)(xq); xq += XSTRIDE;   // x(t+2) (pad rows at end)
            f32x4 QA[4], QB[4];
            qgates2(a0, a1, w0, w1, Ci, Zv, QA, QB);
            half8 ax = selq ? xv : hz;
            f32x4 P4 = MFMA16(ax, Bx, biasC);
            float hn = cellf2(QA, QB, cS);
            Ci[0] = P4;
            Ci[1] = (f32x4){P4[1], P4[1], P4[1], P4[1]};
            Ci[2] = (f32x4){P4[2], P4[2], P4[2], P4[2]};
            Ci[3] = (f32x4){P4[3], P4[3], P4[3], P4[3]};
            *hwA = (_Float16)hn;                         // h(t+2) -> A0
        }
    }
    // after loop: H_0 (encoder final h) in A0. (Last px used pad x -> unused.)

    // ================= decoder setup =================
    half8 axl = *(const half8*)(xs + (Tt - 1) * XSTRIDE + (col >> 2) * 8);

    // Plain decoder weights (step 0 only) + folded weights W' (steps 1..63).
    half8 wp0[4], wp1[4];
    f32x4 biasp[4];
    #pragma unroll
    for (int Tg = 0; Tg < 4; ++Tg) {
        int g = Tg * 64 + u;
        float sc = (Tg == 2) ? K2LOG2 : LOG2E;
        #pragma unroll
        for (int j = 0; j < 8; ++j) {
            int k0 = q * 8 + j;
            float v0 = dWhh[g * 64 + k0];
            float v1 = dWhh[g * 64 + 32 + k0];
            w0[Tg][j] = (_Float16)(v0 * sc);             // plain (step 0)
            w1[Tg][j] = (_Float16)(v1 * sc);
            float s0 = v0, s1 = v1;                      // fold: W' = Whh + Wih*fcW
            #pragma unroll
            for (int f = 0; f < 8; ++f) {
                float wif = dWih[g * 8 + f];
                s0 = __builtin_fmaf(wif, fcW[f * 64 + k0], s0);
                s1 = __builtin_fmaf(wif, fcW[f * 64 + 32 + k0], s1);
            }
            wp0[Tg][j] = (_Float16)(s0 * sc);
            wp1[Tg][j] = (_Float16)(s1 * sc);
        }
        float bb = dbih[g] + dbhh[g];
        float bp = bb;                                   // b' = b + Wih*fcb
        #pragma unroll
        for (int f = 0; f < 8; ++f) bp = __builtin_fmaf(dWih[g * 8 + f], fcb[f], bp);
        biasp[Tg] = (f32x4){bp * sc, bp * sc, bp * sc, bp * sc};
    }
    // px fragments for decoder step 0 (x = x_last, dWih/dbias)
    {
        #pragma unroll
        for (int j = 0; j < 8; ++j)
            Bx[j] = (_Float16)(dWih[(q * 64 + u) * 8 + j] * ((q == 2) ? K2LOG2 : LOG2E));
        #pragma unroll
        for (int r = 0; r < 4; ++r)
            biasC[r] = (dbih[r * 64 + u] + dbhh[r * 64 + u]) * ((r == 2) ? K2LOG2 : LOG2E);
    }
    // fc fragments: pred[b][f] = sum_u h[b][u]*fcW[f][u] + fcb[f]
    half8 wf0, wf1;
    f32x4 biasf;
    {
        #pragma unroll
        for (int j = 0; j < 8; ++j) {
            wf0[j] = (col < 8) ? (_Float16)fcW[col * 64 + q * 8 + j]      : (_Float16)0.f;
            wf1[j] = (col < 8) ? (_Float16)fcW[col * 64 + 32 + q * 8 + j] : (_Float16)0.f;
        }
        float fb = (col < 8) ? fcb[col] : 0.f;
        biasf = (f32x4){fb, fb, fb, fb};
    }

    float* predbuf = (float*)xs;                         // 8 KB alias over dead xs
    const bool pw = (wv == 0) && (col < 8);              // pred writer lanes

    // ---- decoder step 0: plain path, x = x_last; px hoisted off-CP ----
    {
        half8 ax = selq ? axl : hz;
        f32x4 P4 = MFMA16(ax, Bx, biasC);
        Ci[0] = P4;
        Ci[1] = (f32x4){P4[1], P4[1], P4[1], P4[1]};
        Ci[2] = (f32x4){P4[2], P4[2], P4[2], P4[2]};
        Ci[3] = (f32x4){P4[3], P4[3], P4[3], P4[3]};
    }
    __syncthreads();                                     // H_0 visible (A0)
    {
        half8 a0 = *(const half8*)(arA);
        half8 a1 = *(const half8*)(arA + 32);
        f32x4 QA[4], QB[4];
        qgates2(a0, a1, w0, w1, Ci, Zv, QA, QB);
        float hn = cellf2(QA, QB, cS);
        *hwB = (_Float16)hn;                             // H_1 -> A1
    }

    // ---- decoder steps 1..63: pure h-recurrence (folded W'), pred in shadow ----
    for (int p = 1; p < Pp; ++p) {
        __syncthreads();                                 // H_p visible
        const _Float16* ar = (p & 1) ? arB : arA;
        _Float16*       hw = (p & 1) ? hwA : hwB;
        half8 a0 = *(const half8*)(ar);
        half8 a1 = *(const half8*)(ar + 32);
        f32x4 QA[4], QB[4];
        qgates2(a0, a1, wp0, wp1, biasp, Zv, QA, QB);    // C-init = biasp (static)
        // shadow: pred(p-1) = fc(H_p), issued into the Qg-latency gap
        f32x4 F = MFMA16(a0, wf0, biasf);
        F       = MFMA16(a1, wf1, F);
        float hn = cellf2(QA, QB, cS);
        *hw = (_Float16)hn;                              // H_{p+1}
        if (pw) predbuf[q * (Pp * Ff) + (p - 1) * Ff + col] = F[0];
    }

    // ---- epilogue: pred(63) = fc(H_64) (H_64 in A0: p=63 odd wrote hwA) ----
    __syncthreads();
    {
        half8 a0 = *(const half8*)(arA);
        half8 a1 = *(const half8*)(arA + 32);
        f32x4 F = MFMA16(a0, wf0, biasf);
        F       = MFMA16(a1, wf1, F);
        if (pw) predbuf[q * (Pp * Ff) + (Pp - 1) * Ff + col] = F[0];
    }
    __syncthreads();

    // ================= flush preds: LDS -> global, coalesced float4 =================
    {
        f32x4* out4 = (f32x4*)out + (size_t)b0 * (Pp * Ff / 4);
        const f32x4* pb4 = (const f32x4*)predbuf;
        for (int i = tid; i < MB * Pp * Ff / 4; i += 256)
            out4[i] = pb4[i];
    }
}

extern "C" void kernel_launch(void* const* d_in, const int* in_sizes, int n_in,
                              void* d_out, int out_size, void* d_ws, size_t ws_size,
                              hipStream_t stream) {
    (void)in_sizes; (void)n_in; (void)d_ws; (void)ws_size; (void)out_size;
    hipLaunchKernelGGL(seq2seq_v15, dim3(NBLK), dim3(256), 0, stream,
                       (const float*)d_in[0],
                       (const float*)d_in[1], (const float*)d_in[2],
                       (const float*)d_in[3], (const float*)d_in[4],
                       (const float*)d_in[5], (const float*)d_in[6],
                       (const float*)d_in[7], (const float*)d_in[8],
                       (const float*)d_in[9], (const float*)d_in[10],
                       (float*)d_out);
}

// Round 4
// 218.387 us; speedup vs baseline: 1.5155x; 1.5155x over previous
//
#include <hip/hip_runtime.h>

// Seq2SeqLSTM: H=64, F=8, T=512, P=64, B=1024, fp32 in/out.
// R16 = R13 minus its item (4) h-write swizzle (which doubled ds_read_b128
// conflicts: 4.96M->9.68M = +7.6us, the whole R13 regression). Everything
// else is the R12 champion structure:
//   - qgates: MFMA accumulator-chained pairs g,g,i,i,f,f,o,o (C-forwarding
//     fast path; g-gate heads the longest cell dependency).
//   - cellf: h = fma(-2*so, rcp(1+e^{2c}), so); clamp via v_med3_f32.
//   - shadow MFMAs (pchain / decoder fc) between gate MFMAs and cell VALU.
//   - ROWS=72 (16B-aligned rows; the 4.96M conflicts are ~34cy/step, cheaper
//     than any swizzle tried so far: R13 read-side +19us, R15 ROWS=68
//     broke b128 alignment -> +110us).
// REVERTED experiments (measured): R14 pdot on VALU pipe (+25us: slow-pipe
// in-order issue), R15 px-fold + split chains + ROWS=68 (+110us).
// Topology: MB=4 over 256 blocks; lane (q,col) owns cell (batch q, unit
// wv*16+col); batch b at A-row 4b so C/D row=4q+0 puts gates in acc[.][0];
// fp16 weights/h/x pre-scaled by log2e (2*log2e for g-gate); fused-rcp cell.

#define Hh 64
#define Ff 8
#define Tt 512
#define Pp 64
#define BATCH 1024
#define MB 4
#define NBLK (BATCH / MB)   // 256 blocks
#define ROWS 72             // halves per A row (64 + 8 pad)
#define ABUF (16 * ROWS + 64)
#define XSTRIDE 32          // halves per x step-row: 4 batches * 8

typedef __attribute__((ext_vector_type(8))) _Float16 half8;
typedef __attribute__((ext_vector_type(4))) _Float16 half4;
typedef __attribute__((ext_vector_type(4))) float f32x4;

#define LOG2E  1.44269504088896340736f
#define K2LOG2 2.88538008177792681472f   // 2*log2e

#define MFMA16(a, b, c) __builtin_amdgcn_mfma_f32_16x16x32_f16(a, b, c, 0, 0, 0)

__device__ __forceinline__ float rcp_(float x)  { return __builtin_amdgcn_rcpf(x); }
__device__ __forceinline__ float exp2_(float x) { return __builtin_amdgcn_exp2f(x); }
// A-row swizzle (halves): rows 4b (writers) keep offset 0.
__device__ __forceinline__ int arow_base(int m) { return m * ROWS + (m & 3) * 16; }

// B-fragments: 4 gate tiles, fp16, log2e-pre-scaled (2*log2e for g-gate).
// B layout (16x16x32): lane holds B[k = kc*32 + q*8 + j][n = col].
__device__ __forceinline__ void load_wfrags(
    const float* __restrict__ Whh, const float* __restrict__ Wih,
    int wv, int q, int col, half8 w0[4], half8 w1[4], half8 wx[4])
{
    #pragma unroll
    for (int Tg = 0; Tg < 4; ++Tg) {
        int g = Tg * 64 + wv * 16 + col;
        float sc = (Tg == 2) ? K2LOG2 : LOG2E;
        const float* r0 = Whh + g * 64 + q * 8;
        #pragma unroll
        for (int j = 0; j < 8; ++j) {
            w0[Tg][j] = (_Float16)(r0[j] * sc);
            w1[Tg][j] = (_Float16)(r0[32 + j] * sc);
            wx[Tg][j] = (q == 0) ? (_Float16)(Wih[g * 8 + j] * sc) : (_Float16)0.f;
        }
    }
}

// P[Tg] = x-contribution + bias (C-init). Off the critical path.
__device__ __forceinline__ void pchain(half8 ax, const half8 wx[4],
                                       const f32x4 biasv[4], f32x4 P[4])
{
    P[2] = MFMA16(ax, wx[2], biasv[2]);
    P[0] = MFMA16(ax, wx[0], biasv[0]);
    P[1] = MFMA16(ax, wx[1], biasv[1]);
    P[3] = MFMA16(ax, wx[3], biasv[3]);
}

// Gate MFMAs: accumulator-chained pairs, g-gate first (longest downstream dep).
__device__ __forceinline__ void qgates(half8 a0, half8 a1,
    const half8 w0[4], const half8 w1[4], const f32x4 P[4], f32x4 Q[4])
{
    Q[2] = MFMA16(a0, w0[2], P[2]);
    Q[2] = MFMA16(a1, w1[2], Q[2]);
    Q[0] = MFMA16(a0, w0[0], P[0]);
    Q[0] = MFMA16(a1, w1[0], Q[0]);
    Q[1] = MFMA16(a0, w0[1], P[1]);
    Q[1] = MFMA16(a1, w1[1], Q[1]);
    Q[3] = MFMA16(a0, w0[3], P[3]);
    Q[3] = MFMA16(a1, w1[3], Q[3]);
}

// Fused-rcp cell. Spine: eg -> it -> cS fma -> med3 -> ec -> rc -> fma -> cvt.
__device__ __forceinline__ float cellf(const f32x4 Q[4], float& cS)
{
    float eg = exp2_(Q[2][0]);            // e^{2g} (g-row pre-scaled 2*log2e)
    float ei = exp2_(-Q[0][0]);
    float it = (eg - 1.f) * rcp_((1.f + ei) * (1.f + eg));   // si*tanh(g)
    float ef = exp2_(-Q[1][0]);
    float sf = rcp_(1.f + ef);
    float eo = exp2_(-Q[3][0]);
    float so   = rcp_(1.f + eo);          // sigmoid(o), off-spine
    float m2so = -2.f * so;
    cS = __builtin_fmaf(sf, cS, K2LOG2 * it);                // cS = 2*log2e*c
    float cc = __builtin_amdgcn_fmed3f(cS, -60.f, 60.f);     // exp2 guard
    float ec = exp2_(cc);                                    // e^{2c}
    float rc = rcp_(1.f + ec);
    return __builtin_fmaf(m2so, rc, so);  // so*tanh(c) = so*(1 - 2/(1+e^{2c}))
}

__global__ __launch_bounds__(256, 1)
void seq2seq_v16(const float* __restrict__ x_seq,
                 const float* __restrict__ eWih, const float* __restrict__ eWhh,
                 const float* __restrict__ ebih, const float* __restrict__ ebhh,
                 const float* __restrict__ dWih, const float* __restrict__ dWhh,
                 const float* __restrict__ dbih, const float* __restrict__ dbhh,
                 const float* __restrict__ fcW,  const float* __restrict__ fcb,
                 float* __restrict__ out)
{
    __shared__ __align__(16) _Float16 xs[(Tt + 2) * XSTRIDE];  // 32.9 KB; predbuf alias
    __shared__ __align__(16) _Float16 A0[ABUF];
    __shared__ __align__(16) _Float16 A1[ABUF];

    const int tid  = threadIdx.x;
    const int wv   = tid >> 6;
    const int lane = tid & 63;
    const int q    = lane >> 4;
    const int col  = lane & 15;
    const int u    = wv * 16 + col;
    const int b0   = blockIdx.x * MB;

    half8 w0[4], w1[4], wx[4];
    load_wfrags(eWhh, eWih, wv, q, col, w0, w1, wx);
    f32x4 biasv[4];
    #pragma unroll
    for (int Tg = 0; Tg < 4; ++Tg) {
        int g = Tg * 64 + u;
        float sc = (Tg == 2) ? K2LOG2 : LOG2E;
        float bv = (ebih[g] + ebhh[g]) * sc;
        biasv[Tg] = (f32x4){bv, bv, bv, bv};
    }

    // init: zero A buffers + xs pad rows, stage x (fp32 -> fp16)
    { int* Z0 = (int*)A0; int* Z1 = (int*)A1;
      for (int i = tid; i < ABUF / 2; i += 256) { Z0[i] = 0; Z1[i] = 0; } }
    if (tid < 32) ((int*)xs)[Tt * 16 + tid] = 0;         // zero 2 pad rows
    for (int i = tid; i < MB * Tt * 2; i += 256) {       // 4096 float4s
        int b   = i >> 10;
        int rem = i & 1023;
        int t   = rem >> 1;
        int f4  = (rem & 1) * 4;
        const float* src = x_seq + ((size_t)(b0 + b) * Tt + t) * Ff + f4;
        half4 s = { (_Float16)src[0], (_Float16)src[1], (_Float16)src[2], (_Float16)src[3] };
        *(half4*)(&xs[t * XSTRIDE + b * 8 + f4]) = s;
    }
    __syncthreads();                                     // staging visible

    // per-lane hoisted pointers (R12 addressing: swizzled A reads via
    // arow_base; writers at rows 4b, swizzle 0; NO extra swizzle).
    const _Float16* arA = A0 + arow_base(col) + q * 8;
    const _Float16* arB = A1 + arow_base(col) + q * 8;
    _Float16* hwA = A0 + 4 * q * ROWS + u;
    _Float16* hwB = A1 + 4 * q * ROWS + u;
    const _Float16* xq = xs + (col >> 2) * 8;            // x walker (broadcast groups)

    float cS = 0.f;
    f32x4 P[4];
    {   half8 ax = *(const half8*)(xq);                  // x(0)
        pchain(ax, wx, biasv, P);                        // P for step 0
        xq += XSTRIDE; }

    // ============ encoder: 512 steps, barrier at top, P one step ahead ============
    for (int t = 0; t < Tt; t += 2) {
        __syncthreads();                                 // h(t) visible (A0)
        {
            half8 a0 = *(const half8*)(arA);
            half8 a1 = *(const half8*)(arA + 32);
            half8 ax = *(const half8*)(xq); xq += XSTRIDE;   // x(t+1), off-CP
            f32x4 Q[4];
            qgates(a0, a1, w0, w1, P, Q);
            pchain(ax, wx, biasv, P);                    // fills Qg-latency gap
            float hn = cellf(Q, cS);
            *hwB = (_Float16)hn;                         // h(t+1) -> A1
        }
        __syncthreads();                                 // h(t+1) visible (A1)
        {
            half8 a0 = *(const half8*)(arB);
            half8 a1 = *(const half8*)(arB + 32);
            half8 ax = *(const half8*)(xq); xq += XSTRIDE;   // x(t+2) (pad rows at end)
            f32x4 Q[4];
            qgates(a0, a1, w0, w1, P, Q);
            pchain(ax, wx, biasv, P);
            float hn = cellf(Q, cS);
            *hwA = (_Float16)hn;                         // h(t+2) -> A0
        }
    }
    // after loop: H_0 (encoder final h) in A0.

    // ================= decoder setup =================
    half8 axl = *(const half8*)(xs + (Tt - 1) * XSTRIDE + (col >> 2) * 8);

    // Plain decoder weights (step 0 only) + folded weights W' (steps 1..63).
    half8 wp0[4], wp1[4];
    f32x4 biasp[4];
    #pragma unroll
    for (int Tg = 0; Tg < 4; ++Tg) {
        int g = Tg * 64 + u;
        float sc = (Tg == 2) ? K2LOG2 : LOG2E;
        #pragma unroll
        for (int j = 0; j < 8; ++j) {
            int k0 = q * 8 + j;
            float v0 = dWhh[g * 64 + k0];
            float v1 = dWhh[g * 64 + 32 + k0];
            w0[Tg][j] = (_Float16)(v0 * sc);             // plain (step 0)
            w1[Tg][j] = (_Float16)(v1 * sc);
            wx[Tg][j] = (q == 0) ? (_Float16)(dWih[g * 8 + j] * sc) : (_Float16)0.f;
            float s0 = v0, s1 = v1;                      // fold: W' = Whh + Wih*fcW
            #pragma unroll
            for (int f = 0; f < 8; ++f) {
                float wif = dWih[g * 8 + f];
                s0 = __builtin_fmaf(wif, fcW[f * 64 + k0], s0);
                s1 = __builtin_fmaf(wif, fcW[f * 64 + 32 + k0], s1);
            }
            wp0[Tg][j] = (_Float16)(s0 * sc);
            wp1[Tg][j] = (_Float16)(s1 * sc);
        }
        float bb = dbih[g] + dbhh[g];
        float bp = bb;                                   // b' = b + Wih*fcb
        #pragma unroll
        for (int f = 0; f < 8; ++f) bp = __builtin_fmaf(dWih[g * 8 + f], fcb[f], bp);
        biasv[Tg] = (f32x4){bb * sc, bb * sc, bb * sc, bb * sc};
        biasp[Tg] = (f32x4){bp * sc, bp * sc, bp * sc, bp * sc};
    }
    // fc fragments: pred[b][f] = sum_u h[b][u]*fcW[f][u] + fcb[f]
    half8 wf0, wf1;
    f32x4 biasf;
    {
        #pragma unroll
        for (int j = 0; j < 8; ++j) {
            wf0[j] = (col < 8) ? (_Float16)fcW[col * 64 + q * 8 + j]      : (_Float16)0.f;
            wf1[j] = (col < 8) ? (_Float16)fcW[col * 64 + 32 + q * 8 + j] : (_Float16)0.f;
        }
        float fb = (col < 8) ? fcb[col] : 0.f;
        biasf = (f32x4){fb, fb, fb, fb};
    }

    float* predbuf = (float*)xs;                         // 8 KB alias over dead xs
    const bool pw = (wv == 0) && (col < 8);              // pred writer lanes

    // ---- decoder step 0: plain path, x = x_last; pchain hoisted off-CP ----
    pchain(axl, wx, biasv, P);
    __syncthreads();                                     // H_0 visible (A0)
    {
        half8 a0 = *(const half8*)(arA);
        half8 a1 = *(const half8*)(arA + 32);
        f32x4 Q[4];
        qgates(a0, a1, w0, w1, P, Q);
        float hn = cellf(Q, cS);
        *hwB = (_Float16)hn;                             // H_1 -> A1
    }

    // ---- decoder steps 1..63: pure h-recurrence (folded W'), pred in shadow ----
    for (int p = 1; p < Pp; ++p) {
        __syncthreads();                                 // H_p visible
        const _Float16* ar = (p & 1) ? arB : arA;
        _Float16*       hw = (p & 1) ? hwA : hwB;
        half8 a0 = *(const half8*)(ar);
        half8 a1 = *(const half8*)(ar + 32);
        f32x4 Q[4];
        qgates(a0, a1, wp0, wp1, biasp, Q);              // CP: same as encoder
        // shadow: pred(p-1) = fc(H_p), issued into the Qg-latency gap
        f32x4 F = MFMA16(a0, wf0, biasf);
        F       = MFMA16(a1, wf1, F);
        float hn = cellf(Q, cS);
        *hw = (_Float16)hn;                              // H_{p+1}
        if (pw) predbuf[q * (Pp * Ff) + (p - 1) * Ff + col] = F[0];
    }

    // ---- epilogue: pred(63) = fc(H_64) (H_64 in A0: p=63 odd wrote hwA) ----
    __syncthreads();
    {
        half8 a0 = *(const half8*)(arA);
        half8 a1 = *(const half8*)(arA + 32);
        f32x4 F = MFMA16(a0, wf0, biasf);
        F       = MFMA16(a1, wf1, F);
        if (pw) predbuf[q * (Pp * Ff) + (Pp - 1) * Ff + col] = F[0];
    }
    __syncthreads();

    // ================= flush preds: LDS -> global, coalesced float4 =================
    {
        f32x4* out4 = (f32x4*)out + (size_t)b0 * (Pp * Ff / 4);
        const f32x4* pb4 = (const f32x4*)predbuf;
        for (int i = tid; i < MB * Pp * Ff / 4; i += 256)
            out4[i] = pb4[i];
    }
}

extern "C" void kernel_launch(void* const* d_in, const int* in_sizes, int n_in,
                              void* d_out, int out_size, void* d_ws, size_t ws_size,
                              hipStream_t stream) {
    (void)in_sizes; (void)n_in; (void)d_ws; (void)ws_size; (void)out_size;
    hipLaunchKernelGGL(seq2seq_v16, dim3(NBLK), dim3(256), 0, stream,
                       (const float*)d_in[0],
                       (const float*)d_in[1], (const float*)d_in[2],
                       (const float*)d_in[3], (const float*)d_in[4],
                       (const float*)d_in[5], (const float*)d_in[6],
                       (const float*)d_in[7], (const float*)d_in[8],
                       (const float*)d_in[9], (const float*)d_in[10],
                       (float*)d_out);
}

// Round 5
// 218.079 us; speedup vs baseline: 1.5176x; 1.0014x over previous
//
#include <hip/hip_runtime.h>

// Seq2SeqLSTM: H=64, F=8, T=512, P=64, B=1024, fp32 in/out.
// R17 = R16 (confirmed champion, ~160us hot) + ONE change:
//   ZERO-ROW BROADCAST READS: the A-matrix has only 4 real rows (batch b at
//   row 4b); lanes with col%4!=0 (48 of 64) were ds_read_b128-ing known
//   zeros -> 8KB/step/CU of LDS return traffic (~64cy on the post-barrier
//   critical path at 128B/cy). Those lanes now all read the SAME never-
//   written zero row (row 1): same-address LDS reads broadcast (~free), so
//   return traffic drops to ~2.1KB (~17cy). Real lanes (col%4==0) have
//   swizzle offset 0 and land on banks 4(col+q)%32 = 2-way (free, m136).
//   No divergence, no extra VALU, ~6-line diff vs R16.
// Structure (R12/R16 champion): MB=4 over 256 blocks; lane (q,col) owns cell
// (batch q, unit wv*16+col); batch b at A-row 4b so C/D row=4q+0 puts gates
// in acc[.][0]; qgates chained pairs g,g,i,i,f,f,o,o; shadow pchain/fc MFMAs
// in the Qg-latency gap; fused-rcp cell with med3 guard; fp16 weights/h/x
// pre-scaled by log2e (2*log2e for g-gate); decoder folded W'=Whh+Wih*fcW.
// REVERTED (measured): R13 h-write swizzle (+7.6us read conflicts), R14 VALU
// pdot (+25us in-order slow-pipe), R15 px-fold/ROWS=68 (+110us alignment).

#define Hh 64
#define Ff 8
#define Tt 512
#define Pp 64
#define BATCH 1024
#define MB 4
#define NBLK (BATCH / MB)   // 256 blocks
#define ROWS 72             // halves per A row (64 + 8 pad)
#define ABUF (16 * ROWS + 64)
#define XSTRIDE 32          // halves per x step-row: 4 batches * 8

typedef __attribute__((ext_vector_type(8))) _Float16 half8;
typedef __attribute__((ext_vector_type(4))) _Float16 half4;
typedef __attribute__((ext_vector_type(4))) float f32x4;

#define LOG2E  1.44269504088896340736f
#define K2LOG2 2.88538008177792681472f   // 2*log2e

#define MFMA16(a, b, c) __builtin_amdgcn_mfma_f32_16x16x32_f16(a, b, c, 0, 0, 0)

__device__ __forceinline__ float rcp_(float x)  { return __builtin_amdgcn_rcpf(x); }
__device__ __forceinline__ float exp2_(float x) { return __builtin_amdgcn_exp2f(x); }

// B-fragments: 4 gate tiles, fp16, log2e-pre-scaled (2*log2e for g-gate).
// B layout (16x16x32): lane holds B[k = kc*32 + q*8 + j][n = col].
__device__ __forceinline__ void load_wfrags(
    const float* __restrict__ Whh, const float* __restrict__ Wih,
    int wv, int q, int col, half8 w0[4], half8 w1[4], half8 wx[4])
{
    #pragma unroll
    for (int Tg = 0; Tg < 4; ++Tg) {
        int g = Tg * 64 + wv * 16 + col;
        float sc = (Tg == 2) ? K2LOG2 : LOG2E;
        const float* r0 = Whh + g * 64 + q * 8;
        #pragma unroll
        for (int j = 0; j < 8; ++j) {
            w0[Tg][j] = (_Float16)(r0[j] * sc);
            w1[Tg][j] = (_Float16)(r0[32 + j] * sc);
            wx[Tg][j] = (q == 0) ? (_Float16)(Wih[g * 8 + j] * sc) : (_Float16)0.f;
        }
    }
}

// P[Tg] = x-contribution + bias (C-init). Off the critical path.
__device__ __forceinline__ void pchain(half8 ax, const half8 wx[4],
                                       const f32x4 biasv[4], f32x4 P[4])
{
    P[2] = MFMA16(ax, wx[2], biasv[2]);
    P[0] = MFMA16(ax, wx[0], biasv[0]);
    P[1] = MFMA16(ax, wx[1], biasv[1]);
    P[3] = MFMA16(ax, wx[3], biasv[3]);
}

// Gate MFMAs: accumulator-chained pairs, g-gate first (longest downstream dep).
__device__ __forceinline__ void qgates(half8 a0, half8 a1,
    const half8 w0[4], const half8 w1[4], const f32x4 P[4], f32x4 Q[4])
{
    Q[2] = MFMA16(a0, w0[2], P[2]);
    Q[2] = MFMA16(a1, w1[2], Q[2]);
    Q[0] = MFMA16(a0, w0[0], P[0]);
    Q[0] = MFMA16(a1, w1[0], Q[0]);
    Q[1] = MFMA16(a0, w0[1], P[1]);
    Q[1] = MFMA16(a1, w1[1], Q[1]);
    Q[3] = MFMA16(a0, w0[3], P[3]);
    Q[3] = MFMA16(a1, w1[3], Q[3]);
}

// Fused-rcp cell. Spine: eg -> it -> cS fma -> med3 -> ec -> rc -> fma -> cvt.
__device__ __forceinline__ float cellf(const f32x4 Q[4], float& cS)
{
    float eg = exp2_(Q[2][0]);            // e^{2g} (g-row pre-scaled 2*log2e)
    float ei = exp2_(-Q[0][0]);
    float it = (eg - 1.f) * rcp_((1.f + ei) * (1.f + eg));   // si*tanh(g)
    float ef = exp2_(-Q[1][0]);
    float sf = rcp_(1.f + ef);
    float eo = exp2_(-Q[3][0]);
    float so   = rcp_(1.f + eo);          // sigmoid(o), off-spine
    float m2so = -2.f * so;
    cS = __builtin_fmaf(sf, cS, K2LOG2 * it);                // cS = 2*log2e*c
    float cc = __builtin_amdgcn_fmed3f(cS, -60.f, 60.f);     // exp2 guard
    float ec = exp2_(cc);                                    // e^{2c}
    float rc = rcp_(1.f + ec);
    return __builtin_fmaf(m2so, rc, so);  // so*tanh(c) = so*(1 - 2/(1+e^{2c}))
}

__global__ __launch_bounds__(256, 1)
void seq2seq_v17(const float* __restrict__ x_seq,
                 const float* __restrict__ eWih, const float* __restrict__ eWhh,
                 const float* __restrict__ ebih, const float* __restrict__ ebhh,
                 const float* __restrict__ dWih, const float* __restrict__ dWhh,
                 const float* __restrict__ dbih, const float* __restrict__ dbhh,
                 const float* __restrict__ fcW,  const float* __restrict__ fcb,
                 float* __restrict__ out)
{
    __shared__ __align__(16) _Float16 xs[(Tt + 2) * XSTRIDE];  // 32.9 KB; predbuf alias
    __shared__ __align__(16) _Float16 A0[ABUF];
    __shared__ __align__(16) _Float16 A1[ABUF];

    const int tid  = threadIdx.x;
    const int wv   = tid >> 6;
    const int lane = tid & 63;
    const int q    = lane >> 4;
    const int col  = lane & 15;
    const int u    = wv * 16 + col;
    const int b0   = blockIdx.x * MB;

    half8 w0[4], w1[4], wx[4];
    load_wfrags(eWhh, eWih, wv, q, col, w0, w1, wx);
    f32x4 biasv[4];
    #pragma unroll
    for (int Tg = 0; Tg < 4; ++Tg) {
        int g = Tg * 64 + u;
        float sc = (Tg == 2) ? K2LOG2 : LOG2E;
        float bv = (ebih[g] + ebhh[g]) * sc;
        biasv[Tg] = (f32x4){bv, bv, bv, bv};
    }

    // init: zero A buffers + xs pad rows, stage x (fp32 -> fp16)
    { int* Z0 = (int*)A0; int* Z1 = (int*)A1;
      for (int i = tid; i < ABUF / 2; i += 256) { Z0[i] = 0; Z1[i] = 0; } }
    if (tid < 32) ((int*)xs)[Tt * 16 + tid] = 0;         // zero 2 pad rows
    for (int i = tid; i < MB * Tt * 2; i += 256) {       // 4096 float4s
        int b   = i >> 10;
        int rem = i & 1023;
        int t   = rem >> 1;
        int f4  = (rem & 1) * 4;
        const float* src = x_seq + ((size_t)(b0 + b) * Tt + t) * Ff + f4;
        half4 s = { (_Float16)src[0], (_Float16)src[1], (_Float16)src[2], (_Float16)src[3] };
        *(half4*)(&xs[t * XSTRIDE + b * 8 + f4]) = s;
    }
    __syncthreads();                                     // staging visible

    // per-lane hoisted pointers.
    // A-READS: only rows 4b are real (batch b); lanes col%4!=0 would read
    // known zeros, so they ALL point at zero row 1 (halves 72..143, zero-init,
    // never written: writers hit rows {0,4,8,12} only). Same-address reads
    // broadcast -> LDS return traffic ~4x smaller. Real lanes (col%4==0)
    // read A[row=col][k=q*8..]: banks 4(col+q)%32, 2-way (free).
    const bool rl = ((col & 3) == 0);                    // real-read lanes
    const int rbase = rl ? (col * ROWS) : ROWS;          // zero-lanes -> row 1
    const _Float16* arA = A0 + rbase + q * 8;
    const _Float16* arB = A1 + rbase + q * 8;
    _Float16* hwA = A0 + 4 * q * ROWS + u;               // writers: rows 4q
    _Float16* hwB = A1 + 4 * q * ROWS + u;
    const _Float16* xq = xs + (col >> 2) * 8;            // x walker (broadcast groups)

    float cS = 0.f;
    f32x4 P[4];
    {   half8 ax = *(const half8*)(xq);                  // x(0)
        pchain(ax, wx, biasv, P);                        // P for step 0
        xq += XSTRIDE; }

    // ============ encoder: 512 steps, barrier at top, P one step ahead ============
    for (int t = 0; t < Tt; t += 2) {
        __syncthreads();                                 // h(t) visible (A0)
        {
            half8 a0 = *(const half8*)(arA);
            half8 a1 = *(const half8*)(arA + 32);
            half8 ax = *(const half8*)(xq); xq += XSTRIDE;   // x(t+1), off-CP
            f32x4 Q[4];
            qgates(a0, a1, w0, w1, P, Q);
            pchain(ax, wx, biasv, P);                    // fills Qg-latency gap
            float hn = cellf(Q, cS);
            *hwB = (_Float16)hn;                         // h(t+1) -> A1
        }
        __syncthreads();                                 // h(t+1) visible (A1)
        {
            half8 a0 = *(const half8*)(arB);
            half8 a1 = *(const half8*)(arB + 32);
            half8 ax = *(const half8*)(xq); xq += XSTRIDE;   // x(t+2) (pad rows at end)
            f32x4 Q[4];
            qgates(a0, a1, w0, w1, P, Q);
            pchain(ax, wx, biasv, P);
            float hn = cellf(Q, cS);
            *hwA = (_Float16)hn;                         // h(t+2) -> A0
        }
    }
    // after loop: H_0 (encoder final h) in A0.

    // ================= decoder setup =================
    half8 axl = *(const half8*)(xs + (Tt - 1) * XSTRIDE + (col >> 2) * 8);

    // Plain decoder weights (step 0 only) + folded weights W' (steps 1..63).
    half8 wp0[4], wp1[4];
    f32x4 biasp[4];
    #pragma unroll
    for (int Tg = 0; Tg < 4; ++Tg) {
        int g = Tg * 64 + u;
        float sc = (Tg == 2) ? K2LOG2 : LOG2E;
        #pragma unroll
        for (int j = 0; j < 8; ++j) {
            int k0 = q * 8 + j;
            float v0 = dWhh[g * 64 + k0];
            float v1 = dWhh[g * 64 + 32 + k0];
            w0[Tg][j] = (_Float16)(v0 * sc);             // plain (step 0)
            w1[Tg][j] = (_Float16)(v1 * sc);
            wx[Tg][j] = (q == 0) ? (_Float16)(dWih[g * 8 + j] * sc) : (_Float16)0.f;
            float s0 = v0, s1 = v1;                      // fold: W' = Whh + Wih*fcW
            #pragma unroll
            for (int f = 0; f < 8; ++f) {
                float wif = dWih[g * 8 + f];
                s0 = __builtin_fmaf(wif, fcW[f * 64 + k0], s0);
                s1 = __builtin_fmaf(wif, fcW[f * 64 + 32 + k0], s1);
            }
            wp0[Tg][j] = (_Float16)(s0 * sc);
            wp1[Tg][j] = (_Float16)(s1 * sc);
        }
        float bb = dbih[g] + dbhh[g];
        float bp = bb;                                   // b' = b + Wih*fcb
        #pragma unroll
        for (int f = 0; f < 8; ++f) bp = __builtin_fmaf(dWih[g * 8 + f], fcb[f], bp);
        biasv[Tg] = (f32x4){bb * sc, bb * sc, bb * sc, bb * sc};
        biasp[Tg] = (f32x4){bp * sc, bp * sc, bp * sc, bp * sc};
    }
    // fc fragments: pred[b][f] = sum_u h[b][u]*fcW[f][u] + fcb[f]
    half8 wf0, wf1;
    f32x4 biasf;
    {
        #pragma unroll
        for (int j = 0; j < 8; ++j) {
            wf0[j] = (col < 8) ? (_Float16)fcW[col * 64 + q * 8 + j]      : (_Float16)0.f;
            wf1[j] = (col < 8) ? (_Float16)fcW[col * 64 + 32 + q * 8 + j] : (_Float16)0.f;
        }
        float fb = (col < 8) ? fcb[col] : 0.f;
        biasf = (f32x4){fb, fb, fb, fb};
    }

    float* predbuf = (float*)xs;                         // 8 KB alias over dead xs
    const bool pw = (wv == 0) && (col < 8);              // pred writer lanes

    // ---- decoder step 0: plain path, x = x_last; pchain hoisted off-CP ----
    pchain(axl, wx, biasv, P);
    __syncthreads();                                     // H_0 visible (A0)
    {
        half8 a0 = *(const half8*)(arA);
        half8 a1 = *(const half8*)(arA + 32);
        f32x4 Q[4];
        qgates(a0, a1, w0, w1, P, Q);
        float hn = cellf(Q, cS);
        *hwB = (_Float16)hn;                             // H_1 -> A1
    }

    // ---- decoder steps 1..63: pure h-recurrence (folded W'), pred in shadow ----
    for (int p = 1; p < Pp; ++p) {
        __syncthreads();                                 // H_p visible
        const _Float16* ar = (p & 1) ? arB : arA;
        _Float16*       hw = (p & 1) ? hwA : hwB;
        half8 a0 = *(const half8*)(ar);
        half8 a1 = *(const half8*)(ar + 32);
        f32x4 Q[4];
        qgates(a0, a1, wp0, wp1, biasp, Q);              // CP: same as encoder
        // shadow: pred(p-1) = fc(H_p), issued into the Qg-latency gap
        f32x4 F = MFMA16(a0, wf0, biasf);
        F       = MFMA16(a1, wf1, F);
        float hn = cellf(Q, cS);
        *hw = (_Float16)hn;                              // H_{p+1}
        if (pw) predbuf[q * (Pp * Ff) + (p - 1) * Ff + col] = F[0];
    }

    // ---- epilogue: pred(63) = fc(H_64) (H_64 in A0: p=63 odd wrote hwA) ----
    __syncthreads();
    {
        half8 a0 = *(const half8*)(arA);
        half8 a1 = *(const half8*)(arA + 32);
        f32x4 F = MFMA16(a0, wf0, biasf);
        F       = MFMA16(a1, wf1, F);
        if (pw) predbuf[q * (Pp * Ff) + (Pp - 1) * Ff + col] = F[0];
    }
    __syncthreads();

    // ================= flush preds: LDS -> global, coalesced float4 =================
    {
        f32x4* out4 = (f32x4*)out + (size_t)b0 * (Pp * Ff / 4);
        const f32x4* pb4 = (const f32x4*)predbuf;
        for (int i = tid; i < MB * Pp * Ff / 4; i += 256)
            out4[i] = pb4[i];
    }
}

extern "C" void kernel_launch(void* const* d_in, const int* in_sizes, int n_in,
                              void* d_out, int out_size, void* d_ws, size_t ws_size,
                              hipStream_t stream) {
    (void)in_sizes; (void)n_in; (void)d_ws; (void)ws_size; (void)out_size;
    hipLaunchKernelGGL(seq2seq_v17, dim3(NBLK), dim3(256), 0, stream,
                       (const float*)d_in[0],
                       (const float*)d_in[1], (const float*)d_in[2],
                       (const float*)d_in[3], (const float*)d_in[4],
                       (const float*)d_in[5], (const float*)d_in[6],
                       (const float*)d_in[7], (const float*)d_in[8],
                       (const float*)d_in[9], (const float*)d_in[10],
                       (float*)d_out);
}